// Round 4
// baseline (90.264 us; speedup 1.0000x reference)
//
#include <hip/hip_runtime.h>

// Per-pixel Gaussian RBF voting, separable form:
//   field[c,x,y] = sum_n (exp(-dx^2 k)*v[c,n]) * exp(-dy^2 k)
// FLOP floor: 2 ch * 1M pix * 128 n * 2 = 537 MFLOP -> 3.4 us on fp32 VALU
// (no fp32 MFMA on CDNA4). TX=16 amortizes the per-n exp+dy overhead to
// 14/78 issue cycles; issue-bound estimate ~4.2 us.

constexpr int N = 128;
constexpr int W = 1024;
constexpr int L = 1024;
constexpr float SIGMA = 32.0f;

constexpr int TX = 16;       // x rows per block
constexpr int THREADS = 256;
constexpr int TY = THREADS;  // one y per thread -> 65536 threads = 1 wave/SIMD

__global__ __launch_bounds__(THREADS)
void rbf_field_kernel(const float* __restrict__ v,   // [2][N]
                      const int*   __restrict__ xc,  // [N]
                      const int*   __restrict__ yc,  // [N]
                      float*       __restrict__ out) // [2][W][L]
{
    // sB[n][j]: j in [0,32): c = j>>4, i = j&15 -> exp(-dx^2 k) * v[c][n]
    __shared__ __align__(16) float sB[N][2 * TX];   // 16 KB
    __shared__ float sYc[N];

    const int tid = threadIdx.x;
    const int x0 = blockIdx.x * TX;
    const int y  = blockIdx.y * TY + tid;

    constexpr float kInv = 1.0f / (2.0f * SIGMA * SIGMA);

    if (tid < N) sYc[tid] = (float)yc[tid];

    // Fill sB: 8192 entries, 32 per thread, consecutive -> coalesced LDS writes
    #pragma unroll
    for (int k = 0; k < (N * 2 * TX) / THREADS; ++k) {
        int idx = tid + k * THREADS;
        int n = idx >> 5;
        int j = idx & 31;
        int c = j >> 4;
        int i = j & 15;
        float dx = (float)(x0 + i - xc[n]);
        sB[n][j] = __expf(-dx * dx * kInv) * v[c * N + n];
    }
    __syncthreads();

    float acc[TX][2];
    #pragma unroll
    for (int i = 0; i < TX; ++i) {
        acc[i][0] = 0.0f;
        acc[i][1] = 0.0f;
    }

    const float yf = (float)y;

    // Per n: 32 FMA (64 cyc) + 1 exp (8) + 3 VALU (6); LDS reads are
    // wave-uniform broadcast ds_read_b128 on the DS pipe (overlapped).
    // unroll 2 -> ~156-cycle ILP window to hide LDS latency at 1 wave/SIMD.
    #pragma unroll 2
    for (int n = 0; n < N; ++n) {
        float dy = yf - sYc[n];
        float wy = __expf(-dy * dy * kInv);

        #pragma unroll
        for (int i = 0; i < TX; ++i) {
            acc[i][0] += sB[n][i]      * wy;  // channel 0
            acc[i][1] += sB[n][TX + i] * wy;  // channel 1
        }
    }

    // Store: out[c][x][y]; y consecutive across lanes -> fully coalesced
    #pragma unroll
    for (int c = 0; c < 2; ++c) {
        #pragma unroll
        for (int i = 0; i < TX; ++i) {
            out[(size_t)c * W * L + (size_t)(x0 + i) * L + y] = acc[i][c];
        }
    }
}

extern "C" void kernel_launch(void* const* d_in, const int* in_sizes, int n_in,
                              void* d_out, int out_size, void* d_ws, size_t ws_size,
                              hipStream_t stream) {
    const float* v  = (const float*)d_in[0];  // init_vectors [2][128] fp32
    const int*   xc = (const int*)d_in[1];    // x_coord [128] int32
    const int*   yc = (const int*)d_in[2];    // y_coord [128] int32
    float* out = (float*)d_out;               // [1][2][1024][1024] fp32

    dim3 grid(W / TX, L / TY);   // (64, 4) = 256 blocks -> 1 block/CU
    rbf_field_kernel<<<grid, THREADS, 0, stream>>>(v, xc, yc, out);
}

// Round 5
// 67.991 us; speedup vs baseline: 1.3276x; 1.3276x over previous
//
#include <hip/hip_runtime.h>

// Per-pixel Gaussian RBF voting, separable + center cutoff:
//   field[c,x,y] = sum_n (exp(-dx^2 k)*v[c,n]) * exp(-dy^2 k)
// Cutoff: w(d>=160) <= exp(-12.5) = 3.7e-6; dropping those centers adds
// <= 128*max|v|*3.7e-6 ~ 5e-5 error (threshold 2.3e-3). A 8x256 tile keeps
// centers in a 328x576 box: avg ~23/128 -> 5.5x less work AND 5.5x fewer
// latency-exposed n-iterations (R4 showed the loop is latency-bound).

constexpr int N = 128;
constexpr int W = 1024;
constexpr int L = 1024;
constexpr float SIGMA = 32.0f;
constexpr int RCUT = 160;    // exp(-160^2/(2*32^2)) = 3.7e-6

constexpr int TX = 8;        // x rows per block (best measured config)
constexpr int THREADS = 256;
constexpr int TY = THREADS;  // one y per thread -> 512 blocks = 2 waves/SIMD

__global__ __launch_bounds__(THREADS)
void rbf_field_kernel(const float* __restrict__ v,   // [2][N]
                      const int*   __restrict__ xc,  // [N]
                      const int*   __restrict__ yc,  // [N]
                      float*       __restrict__ out) // [2][W][L]
{
    __shared__ __align__(16) float sB[N][2 * TX];  // compacted: [m][c*TX+i]
    __shared__ float sYc[N];                       // compacted yc
    __shared__ int   sIdx[N];
    __shared__ int   sCnt;

    const int tid = threadIdx.x;
    const int x0 = blockIdx.x * TX;
    const int y0 = blockIdx.y * TY;
    const int y  = y0 + tid;

    constexpr float kInv = 1.0f / (2.0f * SIGMA * SIGMA);

    if (tid == 0) sCnt = 0;
    __syncthreads();

    // Phase 1: compact the centers that can touch this tile
    if (tid < N) {
        int xcn = xc[tid];
        int ycn = yc[tid];
        bool keep = (xcn >= x0 - RCUT) && (xcn <= x0 + TX - 1 + RCUT) &&
                    (ycn >= y0 - RCUT) && (ycn <= y0 + TY - 1 + RCUT);
        if (keep) {
            int m = atomicAdd(&sCnt, 1);
            sIdx[m] = tid;
        }
    }
    __syncthreads();
    const int cnt = sCnt;

    // Phase 2: build sB[m][j] = exp(-dx^2 k) * v[c][n] for kept centers
    for (int base = tid; base < cnt * 2 * TX; base += THREADS) {
        int m = base >> 4;
        int j = base & 15;
        int c = j >> 3;
        int i = j & 7;
        int n = sIdx[m];
        float dx = (float)(x0 + i - xc[n]);
        sB[m][j] = __expf(-dx * dx * kInv) * v[c * N + n];
    }
    if (tid < cnt) sYc[tid] = (float)yc[sIdx[tid]];
    __syncthreads();

    float acc[TX][2];
    #pragma unroll
    for (int i = 0; i < TX; ++i) {
        acc[i][0] = 0.0f;
        acc[i][1] = 0.0f;
    }

    const float yf = (float)y;

    // cnt is block-uniform -> no divergence; LDS reads are wave-uniform
    // broadcasts. ~23 iterations avg instead of 128.
    #pragma unroll 2
    for (int m = 0; m < cnt; ++m) {
        float dy = yf - sYc[m];
        float wy = __expf(-dy * dy * kInv);

        #pragma unroll
        for (int i = 0; i < TX; ++i) {
            acc[i][0] += sB[m][i]      * wy;  // channel 0
            acc[i][1] += sB[m][TX + i] * wy;  // channel 1
        }
    }

    // Store: out[c][x][y]; y consecutive across lanes -> fully coalesced
    #pragma unroll
    for (int c = 0; c < 2; ++c) {
        #pragma unroll
        for (int i = 0; i < TX; ++i) {
            out[(size_t)c * W * L + (size_t)(x0 + i) * L + y] = acc[i][c];
        }
    }
}

extern "C" void kernel_launch(void* const* d_in, const int* in_sizes, int n_in,
                              void* d_out, int out_size, void* d_ws, size_t ws_size,
                              hipStream_t stream) {
    const float* v  = (const float*)d_in[0];  // init_vectors [2][128] fp32
    const int*   xc = (const int*)d_in[1];    // x_coord [128] int32
    const int*   yc = (const int*)d_in[2];    // y_coord [128] int32
    float* out = (float*)d_out;               // [1][2][1024][1024] fp32

    dim3 grid(W / TX, L / TY);   // (128, 4) = 512 blocks -> 2 blocks/CU
    rbf_field_kernel<<<grid, THREADS, 0, stream>>>(v, xc, yc, out);
}

// Round 6
// 66.976 us; speedup vs baseline: 1.3477x; 1.0152x over previous
//
#include <hip/hip_runtime.h>

// Per-pixel Gaussian RBF voting, separable + center cutoff + 2D tiling:
//   field[c,x,y] = sum_n (exp(-dx^2 k)*v[c,n]) * exp(-dy^2 k)
// Cutoff: w(d>=160) <= 3.7e-6 -> dropped-center error <= ~5e-5 (thr 2.3e-3).
// 32x64 pixel tile: cutoff box 352x384 -> avg ~16.5/128 centers kept
// (vs 23 for the 8x256 tile). Decomposition from R3/R5 deltas: harness
// poison/replay floor ~65 us; kernel ~2.7 us (stores 1.3 us HBM-bound).

constexpr int N = 128;
constexpr int W = 1024;
constexpr int L = 1024;
constexpr float SIGMA = 32.0f;
constexpr int RCUT = 160;    // exp(-160^2/(2*32^2)) = 3.7e-6

constexpr int TX = 32;       // x rows per tile
constexpr int TY = 64;       // y cols per tile
constexpr int THREADS = 256; // 4 waves; wave w handles x-rows [w*8, w*8+8)
constexpr int XPT = TX / 4;  // 8 x-rows per thread

__global__ __launch_bounds__(THREADS)
void rbf_field_kernel(const float* __restrict__ v,   // [2][N]
                      const int*   __restrict__ xc,  // [N]
                      const int*   __restrict__ yc,  // [N]
                      float*       __restrict__ out) // [2][W][L]
{
    // sB[m][j]: j in [0,64): c = j>>5, i = j&31 -> exp(-dx^2 k) * v[c][n]
    __shared__ __align__(16) float sB[N][2 * TX];  // 32 KB max
    __shared__ float sYc[N];
    __shared__ int   sIdx[N];
    __shared__ int   sCnt;

    const int tid = threadIdx.x;
    const int g   = tid >> 6;          // wave id: uniform within a wave
    const int ty  = tid & 63;          // y within tile
    const int x0  = blockIdx.x * TX;
    const int y0  = blockIdx.y * TY;

    constexpr float kInv = 1.0f / (2.0f * SIGMA * SIGMA);

    if (tid == 0) sCnt = 0;
    __syncthreads();

    // Phase 1: compact centers whose Gaussian can touch this tile
    if (tid < N) {
        int xcn = xc[tid];
        int ycn = yc[tid];
        bool keep = (xcn >= x0 - RCUT) && (xcn <= x0 + TX - 1 + RCUT) &&
                    (ycn >= y0 - RCUT) && (ycn <= y0 + TY - 1 + RCUT);
        if (keep) {
            int m = atomicAdd(&sCnt, 1);
            sIdx[m] = tid;
        }
    }
    __syncthreads();
    const int cnt = sCnt;

    // Phase 2: sB[m][j] = exp(-dx^2 k) * v[c][n] for kept centers (~4/thread)
    for (int base = tid; base < cnt * 2 * TX; base += THREADS) {
        int m = base >> 6;
        int j = base & 63;
        int c = j >> 5;
        int i = j & 31;
        int n = sIdx[m];
        float dx = (float)(x0 + i - xc[n]);
        sB[m][j] = __expf(-dx * dx * kInv) * v[c * N + n];
    }
    if (tid < cnt) sYc[tid] = (float)yc[sIdx[tid]];
    __syncthreads();

    float acc[XPT][2];
    #pragma unroll
    for (int i = 0; i < XPT; ++i) {
        acc[i][0] = 0.0f;
        acc[i][1] = 0.0f;
    }

    const float yf = (float)(y0 + ty);

    // cnt block-uniform -> no divergence; sB reads wave-uniform (g constant
    // per wave) -> broadcast ds_read, conflict-free. ~16.5 iters avg.
    #pragma unroll 2
    for (int m = 0; m < cnt; ++m) {
        float dy = yf - sYc[m];
        float wy = __expf(-dy * dy * kInv);

        #pragma unroll
        for (int i = 0; i < XPT; ++i) {
            acc[i][0] += sB[m][g * XPT + i]      * wy;  // channel 0
            acc[i][1] += sB[m][TX + g * XPT + i] * wy;  // channel 1
        }
    }

    // Store: lanes have consecutive y -> 256 B per wave-store, coalesced
    #pragma unroll
    for (int c = 0; c < 2; ++c) {
        #pragma unroll
        for (int i = 0; i < XPT; ++i) {
            int x = x0 + g * XPT + i;
            out[(size_t)c * W * L + (size_t)x * L + (y0 + ty)] = acc[i][c];
        }
    }
}

extern "C" void kernel_launch(void* const* d_in, const int* in_sizes, int n_in,
                              void* d_out, int out_size, void* d_ws, size_t ws_size,
                              hipStream_t stream) {
    const float* v  = (const float*)d_in[0];  // init_vectors [2][128] fp32
    const int*   xc = (const int*)d_in[1];    // x_coord [128] int32
    const int*   yc = (const int*)d_in[2];    // y_coord [128] int32
    float* out = (float*)d_out;               // [1][2][1024][1024] fp32

    dim3 grid(W / TX, L / TY);   // (32, 16) = 512 blocks -> 2 blocks/CU
    rbf_field_kernel<<<grid, THREADS, 0, stream>>>(v, xc, yc, out);
}